// Round 19
// baseline (1987.305 us; speedup 1.0000x reference)
//
#include <hip/hip_runtime.h>

// Wav2Vec BLSTM: 4-layer bi-LSTM (B=32, T=1000, H=32, G=128) + mean-pool + fc.
//
// Round 19:
//  GEMM: r18 + As-read conflict fix: per-thread m split into two quads at
//  m and m+64 (16-lane stride 16B = 2-way free) instead of one octet at
//  stride 32B (4-way).
//  LSTM: TWO chains (fwd+bwd of same b) per wave, 32 blocks. Chain B's
//  issue fills chain A's dependency stalls. Plain LDS broadcast (compiler
//  fine-grained lgkmcnt) + verified r15 tail. __launch_bounds__(64,1) for
//  VGPR headroom.

#define TB 1000
#define LOG2E 1.44269504088896340736f

typedef int   v2i __attribute__((ext_vector_type(2)));
typedef float v2f __attribute__((ext_vector_type(2)));

__device__ __forceinline__ float fexp2(float x) {
#if __has_builtin(__builtin_amdgcn_exp2f)
    return __builtin_amdgcn_exp2f(x);
#else
    return exp2f(x);
#endif
}

// returns v[lane ^ 32]; pickx precomputed per-lane (convention-independent)
__device__ __forceinline__ float lane_xor32(float v, bool pickx) {
    v2i r = __builtin_amdgcn_permlane32_swap(__float_as_int(v), __float_as_int(v),
                                             false, false);
    return __int_as_float(pickx ? r[0] : r[1]);
}

// ---------------------------------------------------------------------------
// GEMM: A[32000][K] x W[256][K]^T + (bi+bh), prescale by -log2e (g-rows:
// -2log2e) -> xpT[2*32][128][1000] (dir=1 time-reversed).
// 128m x 128n tile, 256 threads, acc[8n][8m] (m-quads at tx*4 and 64+tx*4),
// BK=32, r10 chunk order.
// ---------------------------------------------------------------------------
__global__ __launch_bounds__(256)
void gemm_proj(const float* __restrict__ A, int K,
               const float* __restrict__ W,
               const float* __restrict__ bi,
               const float* __restrict__ bh,
               float* __restrict__ xpT)
{
    __shared__ __align__(16) float As[32][132];   // [k][m]
    __shared__ __align__(16) float Bs[32][132];   // [k][n]

    const int tid = threadIdx.x;
    const int m0 = blockIdx.x * 128;
    const int n0 = blockIdx.y * 128;
    const int tx = tid & 15;     // m-quads: m = m0 + qd*64 + tx*4 + mi
    const int ty = tid >> 4;     // n-octet: n = n0 + ty*8 + ni

    float acc[8][8];
#pragma unroll
    for (int i = 0; i < 8; ++i)
#pragma unroll
        for (int jj = 0; jj < 8; ++jj) acc[i][jj] = 0.0f;

    const int ar = tid >> 1;           // row 0..127 (for both A and W)
    const int ak = (tid & 1) * 16;     // k-half 0/16

    for (int k0 = 0; k0 < K; k0 += 32) {
        const float* ap = A + (size_t)(m0 + ar) * K + k0 + ak;
        float4 a0 = *(const float4*)(ap + 0);
        float4 a1 = *(const float4*)(ap + 4);
        float4 a2 = *(const float4*)(ap + 8);
        float4 a3 = *(const float4*)(ap + 12);
        const float* wp = W + (size_t)(n0 + ar) * K + k0 + ak;
        float4 w0 = *(const float4*)(wp + 0);
        float4 w1 = *(const float4*)(wp + 4);
        float4 w2 = *(const float4*)(wp + 8);
        float4 w3 = *(const float4*)(wp + 12);

        __syncthreads();
        {
            float av_[16] = {a0.x, a0.y, a0.z, a0.w, a1.x, a1.y, a1.z, a1.w,
                             a2.x, a2.y, a2.z, a2.w, a3.x, a3.y, a3.z, a3.w};
#pragma unroll
            for (int q = 0; q < 16; ++q) As[ak + q][ar] = av_[q];
            float wv_[16] = {w0.x, w0.y, w0.z, w0.w, w1.x, w1.y, w1.z, w1.w,
                             w2.x, w2.y, w2.z, w2.w, w3.x, w3.y, w3.z, w3.w};
#pragma unroll
            for (int q = 0; q < 16; ++q) Bs[ak + q][ar] = wv_[q];
        }
        __syncthreads();

#pragma unroll
        for (int kk = 0; kk < 32; ++kk) {
            float4 av0 = *(const float4*)&As[kk][tx * 4];        // m-quad 0
            float4 av1 = *(const float4*)&As[kk][64 + tx * 4];   // m-quad 1
            float4 bv0 = *(const float4*)&Bs[kk][ty * 8];
            float4 bv1 = *(const float4*)&Bs[kk][ty * 8 + 4];
            float am[8] = {av0.x, av0.y, av0.z, av0.w, av1.x, av1.y, av1.z, av1.w};
            float wn[8] = {bv0.x, bv0.y, bv0.z, bv0.w, bv1.x, bv1.y, bv1.z, bv1.w};
#pragma unroll
            for (int ni = 0; ni < 8; ++ni)
#pragma unroll
                for (int mi = 0; mi < 8; ++mi)
                    acc[ni][mi] = fmaf(am[mi], wn[ni], acc[ni][mi]);
        }
    }

    // epilogue: bias + prescale + transposed (dir=1 time-reversed) store
    const int dir = n0 >> 7;
#pragma unroll
    for (int ni = 0; ni < 8; ++ni) {
        const int n = n0 + ty * 8 + ni;
        const float bias = bi[n] + bh[n];
        const float sc = (((n >> 5) & 3) == 2) ? (-2.0f * LOG2E) : (-LOG2E);
        float* rowp = xpT + ((size_t)(dir * 32 * 128) + (n & 127)) * TB;
#pragma unroll
        for (int qd = 0; qd < 2; ++qd) {
            const int mq = m0 + qd * 64 + tx * 4;
            const int bidx = mq / 1000;       // quad never crosses b (4 | 1000)
            const int ttq = mq - bidx * 1000;
            float* rp = rowp + (size_t)bidx * 128 * TB;
            if (dir == 0) {
                float4 o = {(acc[ni][qd*4+0] + bias) * sc,
                            (acc[ni][qd*4+1] + bias) * sc,
                            (acc[ni][qd*4+2] + bias) * sc,
                            (acc[ni][qd*4+3] + bias) * sc};
                *(float4*)(rp + ttq) = o;
            } else {
                float4 o = {(acc[ni][qd*4+3] + bias) * sc,
                            (acc[ni][qd*4+2] + bias) * sc,
                            (acc[ni][qd*4+1] + bias) * sc,
                            (acc[ni][qd*4+0] + bias) * sc};
                *(float4*)(rp + (TB - 4 - ttq)) = o;
            }
        }
    }
}

// ---------------------------------------------------------------------------
// Recurrence: TWO independent chains (fwd, bwd of the same b) per wave.
// 32 blocks x 64 threads. Lane l owns gate rows r0=(l&31)+(l>=32?64:0),
// r1=r0+32 per chain. Plain LDS broadcast (hsh0/hsh1), compiler-scheduled.
// Gates prescaled (-log2e, g-rows -2log2e): exp2 direct; cs-folded tail.
// ---------------------------------------------------------------------------
template<int MODE>
__global__ __launch_bounds__(64, 1)
void lstm_rec(const float* __restrict__ xpT,  // [64][128][1000] prescaled
              const float* __restrict__ whh,  // [2][128][32]
              float* __restrict__ hout,       // [32][1000][64]
              float* __restrict__ hsum)       // [32][64]
{
    __shared__ __align__(16) float hsh0[32];
    __shared__ __align__(16) float hsh1[32];

    const int b    = blockIdx.x;   // 0..31
    const int lane = threadIdx.x & 63;
    const int j    = lane & 31;
    const int up   = lane >> 5;
    const int r0   = j + up * 64;
    const int r1   = r0 + 32;

    v2i det = __builtin_amdgcn_permlane32_swap(lane, lane, false, false);
    const bool pickx = (det[0] == (lane ^ 32));

    const float sA = up ? (-2.0f * LOG2E) : (-LOG2E);
    const float sB = -LOG2E;

    v2f wa0[16], wb0[16], wa1[16], wb1[16];
#pragma unroll
    for (int d = 0; d < 2; ++d) {
        const float* wp0 = whh + (size_t)(d * 128 + r0) * 32;
        const float* wp1 = whh + (size_t)(d * 128 + r1) * 32;
        v2f* WA = d ? wa1 : wa0;
        v2f* WB = d ? wb1 : wb0;
#pragma unroll
        for (int q = 0; q < 8; ++q) {
            float4 v = *(const float4*)(wp0 + q * 4);
            WA[2 * q + 0][0] = v.x * sA; WA[2 * q + 0][1] = v.y * sA;
            WA[2 * q + 1][0] = v.z * sA; WA[2 * q + 1][1] = v.w * sA;
            float4 u = *(const float4*)(wp1 + q * 4);
            WB[2 * q + 0][0] = u.x * sB; WB[2 * q + 0][1] = u.y * sB;
            WB[2 * q + 1][0] = u.z * sB; WB[2 * q + 1][1] = u.w * sB;
        }
    }

    // chain 0 = fwd (dir 0, blk b); chain 1 = bwd (dir 1, blk 32+b)
    const float* pa0 = xpT + ((size_t)b * 128 + r0) * TB;
    const float* pb0 = xpT + ((size_t)b * 128 + r1) * TB;
    const float* pa1 = xpT + ((size_t)(32 + b) * 128 + r0) * TB;
    const float* pb1 = xpT + ((size_t)(32 + b) * 128 + r1) * TB;

    float4 A0_0 = *(const float4*)(pa0 + 0);
    float4 B0_0 = *(const float4*)(pb0 + 0);
    float4 A1_0 = *(const float4*)(pa0 + 4);
    float4 B1_0 = *(const float4*)(pb0 + 4);
    float4 A0_1 = *(const float4*)(pa1 + 0);
    float4 B0_1 = *(const float4*)(pb1 + 0);
    float4 A1_1 = *(const float4*)(pa1 + 4);
    float4 B1_1 = *(const float4*)(pb1 + 4);

    const float mA = up ?  2.0f : 1.0f;
    const float mB = up ? -1.0f : 0.0f;

    float cs0 = 0.0f, h0 = 0.0f, hacc0 = 0.0f;
    float cs1 = 0.0f, h1 = 0.0f, hacc1 = 0.0f;
    float* hq0 = hout + ((size_t)b * TB) * 64 + j;                    // t=0, +64
    float* hq1 = hout + ((size_t)b * TB + TB - 1) * 64 + 32 + j;      // t=999, -64

    hsh0[j] = 0.0f;
    hsh1[j] = 0.0f;

#define CHAIN_STEP(HS, WA, WB, CS, H, HQ, HSTEP, HACC, GA, GB) do {             \
        v2f hv[16];                                                             \
        _Pragma("unroll")                                                       \
        for (int q = 0; q < 8; ++q) {                                           \
            float4 t = *(const float4*)&HS[q * 4];                              \
            hv[2 * q + 0][0] = t.x; hv[2 * q + 0][1] = t.y;                     \
            hv[2 * q + 1][0] = t.z; hv[2 * q + 1][1] = t.w;                     \
        }                                                                       \
        v2f qa0 = {(GA), 0.0f}, qa1 = {0.f,0.f}, qa2 = {0.f,0.f}, qa3 = {0.f,0.f}; \
        v2f qb0 = {(GB), 0.0f}, qb1 = {0.f,0.f}, qb2 = {0.f,0.f}, qb3 = {0.f,0.f}; \
        _Pragma("unroll")                                                       \
        for (int q = 0; q < 4; ++q) {                                           \
            qa0 = __builtin_elementwise_fma(hv[4*q+0], WA[4*q+0], qa0);         \
            qb0 = __builtin_elementwise_fma(hv[4*q+0], WB[4*q+0], qb0);         \
            qa1 = __builtin_elementwise_fma(hv[4*q+1], WA[4*q+1], qa1);         \
            qb1 = __builtin_elementwise_fma(hv[4*q+1], WB[4*q+1], qb1);         \
            qa2 = __builtin_elementwise_fma(hv[4*q+2], WA[4*q+2], qa2);         \
            qb2 = __builtin_elementwise_fma(hv[4*q+2], WB[4*q+2], qb2);         \
            qa3 = __builtin_elementwise_fma(hv[4*q+3], WA[4*q+3], qa3);         \
            qb3 = __builtin_elementwise_fma(hv[4*q+3], WB[4*q+3], qb3);         \
        }                                                                       \
        v2f sa = (qa0 + qa1) + (qa2 + qa3);                                     \
        v2f sb = (qb0 + qb1) + (qb2 + qb3);                                     \
        float g0 = sa[0] + sa[1];                                               \
        float g1 = sb[0] + sb[1];                                               \
        float s0 = __builtin_amdgcn_rcpf(1.0f + fexp2(g0));                     \
        float v0 = fmaf(mA, s0, mB);   /* lo: sig(i); hi: tanh(g) */            \
        float v1 = __builtin_amdgcn_rcpf(1.0f + fexp2(g1)); /* sig(f)/sig(o) */ \
        float o0 = lane_xor32(v0, pickx);                                       \
        float o1 = lane_xor32(v1, pickx);                                       \
        float P  = v0 * o0;            /* == si*tg in BOTH halves */            \
        float Ps = P * (-2.0f * LOG2E);                                         \
        float sf = up ? o1 : v1;                                                \
        float so = up ? v1 : o1;                                                \
        CS = fmaf(sf, CS, Ps);         /* CS = -2log2e * c */                   \
        float r_ = __builtin_amdgcn_rcpf(1.0f + fexp2(CS));                     \
        float so2 = so + so;                                                    \
        H = fmaf(so2, r_, -so);        /* = so * tanh(c) */                     \
        HS[j] = H;                                                              \
        if (MODE == 0) *HQ = H; else HACC += H;                                 \
        HQ += HSTEP;                                                            \
    } while (0)

#define STEP2(S0A, S0B, S1A, S1B)                                               \
    CHAIN_STEP(hsh0, wa0, wb0, cs0, h0, hq0,  64, hacc0, S0A, S0B);             \
    CHAIN_STEP(hsh1, wa1, wb1, cs1, h1, hq1, -64, hacc1, S1A, S1B);

    for (int it = 0; it < 125; ++it) {
        const int base = it * 8;
        const int offn0 = min(base + 8,  TB - 4);   // clamped, unconditional
        const int offn1 = min(base + 12, TB - 4);
        float4 NA0_0 = *(const float4*)(pa0 + offn0);
        float4 NB0_0 = *(const float4*)(pb0 + offn0);
        float4 NA1_0 = *(const float4*)(pa0 + offn1);
        float4 NB1_0 = *(const float4*)(pb0 + offn1);
        float4 NA0_1 = *(const float4*)(pa1 + offn0);
        float4 NB0_1 = *(const float4*)(pb1 + offn0);
        float4 NA1_1 = *(const float4*)(pa1 + offn1);
        float4 NB1_1 = *(const float4*)(pb1 + offn1);

        STEP2(A0_0.x, B0_0.x, A0_1.x, B0_1.x);
        STEP2(A0_0.y, B0_0.y, A0_1.y, B0_1.y);
        STEP2(A0_0.z, B0_0.z, A0_1.z, B0_1.z);
        STEP2(A0_0.w, B0_0.w, A0_1.w, B0_1.w);
        STEP2(A1_0.x, B1_0.x, A1_1.x, B1_1.x);
        STEP2(A1_0.y, B1_0.y, A1_1.y, B1_1.y);
        STEP2(A1_0.z, B1_0.z, A1_1.z, B1_1.z);
        STEP2(A1_0.w, B1_0.w, A1_1.w, B1_1.w);

        A0_0 = NA0_0; B0_0 = NB0_0; A1_0 = NA1_0; B1_0 = NB1_0;
        A0_1 = NA0_1; B0_1 = NB0_1; A1_1 = NA1_1; B1_1 = NB1_1;
    }
#undef STEP2
#undef CHAIN_STEP

    if (MODE == 1) {
        hsum[b * 64 + j]      = hacc0;
        hsum[b * 64 + 32 + j] = hacc1;
    }
}

// ---------------------------------------------------------------------------
__global__ __launch_bounds__(64)
void final_fc(const float* __restrict__ hsum,
              const float* __restrict__ fcw,
              const float* __restrict__ fcb,
              float* __restrict__ out)
{
    int b = blockIdx.x;
    int l = threadIdx.x;
    float v = hsum[b * 64 + l] * (1.0f / (float)TB) * fcw[l];
#pragma unroll
    for (int off = 32; off > 0; off >>= 1)
        v += __shfl_down(v, off, 64);
    if (l == 0) out[b] = v + fcb[0];
}

// ---------------------------------------------------------------------------
extern "C" void kernel_launch(void* const* d_in, const int* in_sizes, int n_in,
                              void* d_out, int out_size, void* d_ws, size_t ws_size,
                              hipStream_t stream)
{
    const float* x    = (const float*)d_in[0];
    const float* wih0 = (const float*)d_in[1];
    const float* whh0 = (const float*)d_in[2];
    const float* bih0 = (const float*)d_in[3];
    const float* bhh0 = (const float*)d_in[4];
    const float* wih  = (const float*)d_in[5];
    const float* whh  = (const float*)d_in[6];
    const float* bih  = (const float*)d_in[7];
    const float* bhh  = (const float*)d_in[8];
    const float* fcw  = (const float*)d_in[9];
    const float* fcb  = (const float*)d_in[10];
    float* out = (float*)d_out;

    float* ws = (float*)d_ws;
    float* xp = ws;                         // 64*128*1000 floats
    float* hb = ws + 8192000;               // 32*1000*64 floats
    float* hs = ws + 8192000 + 2048000;     // 32*64

    dim3 gb(250, 2);

    gemm_proj<<<gb, 256, 0, stream>>>(x, 1024, wih0, bih0, bhh0, xp);
    lstm_rec<0><<<32, 64, 0, stream>>>(xp, whh0, hb, hs);

    for (int l = 1; l < 4; ++l) {
        const float* wl  = wih + (size_t)(l - 1) * 2 * 128 * 64;
        const float* whl = whh + (size_t)(l - 1) * 2 * 128 * 32;
        const float* b1  = bih + (size_t)(l - 1) * 256;
        const float* b2  = bhh + (size_t)(l - 1) * 256;
        gemm_proj<<<gb, 256, 0, stream>>>(hb, 64, wl, b1, b2, xp);
        if (l == 3) lstm_rec<1><<<32, 64, 0, stream>>>(xp, whl, hb, hs);
        else        lstm_rec<0><<<32, 64, 0, stream>>>(xp, whl, hb, hs);
    }

    final_fc<<<32, 64, 0, stream>>>(hs, fcw, fcb, out);
}

// Round 20
// 1018.094 us; speedup vs baseline: 1.9520x; 1.9520x over previous
//
#include <hip/hip_runtime.h>

// Wav2Vec BLSTM: 4-layer bi-LSTM (B=32, T=1000, H=32, G=128) + mean-pool + fc.
//
// Round 20: consolidation of component-wise best.
//  GEMM = r19 (128x128 tile, 8x8 acc, conflict-free staging writes, and
//  m split into two quads at tx*4 / 64+tx*4 -> 2-way (free) LDS reads).
//  LSTM = r15 verified (1 chain/wave, staged lgkmcnt broadcast, cs-folded
//  tail). r19's 2-chain experiment reverted (VGPR 216 + lgkmcnt FIFO
//  serialization made it 2.3x slower).

#define TB 1000
#define LOG2E 1.44269504088896340736f

typedef int   v2i __attribute__((ext_vector_type(2)));
typedef float v2f __attribute__((ext_vector_type(2)));

__device__ __forceinline__ float fexp2(float x) {
#if __has_builtin(__builtin_amdgcn_exp2f)
    return __builtin_amdgcn_exp2f(x);
#else
    return exp2f(x);
#endif
}

// returns v[lane ^ 32]; pickx precomputed per-lane (convention-independent)
__device__ __forceinline__ float lane_xor32(float v, bool pickx) {
    v2i r = __builtin_amdgcn_permlane32_swap(__float_as_int(v), __float_as_int(v),
                                             false, false);
    return __int_as_float(pickx ? r[0] : r[1]);
}

// ---------------------------------------------------------------------------
// GEMM: A[32000][K] x W[256][K]^T + (bi+bh), prescale by -log2e (g-rows:
// -2log2e) -> xpT[2*32][128][1000] (dir=1 time-reversed).
// 128m x 128n tile, 256 threads, acc[8n][8m] (m-quads at tx*4 and 64+tx*4),
// BK=32, r10 chunk order (the only allocator-safe schedule).
// ---------------------------------------------------------------------------
__global__ __launch_bounds__(256)
void gemm_proj(const float* __restrict__ A, int K,
               const float* __restrict__ W,
               const float* __restrict__ bi,
               const float* __restrict__ bh,
               float* __restrict__ xpT)
{
    __shared__ __align__(16) float As[32][132];   // [k][m]
    __shared__ __align__(16) float Bs[32][132];   // [k][n]

    const int tid = threadIdx.x;
    const int m0 = blockIdx.x * 128;
    const int n0 = blockIdx.y * 128;
    const int tx = tid & 15;     // m-quads: m = m0 + qd*64 + tx*4 + mi
    const int ty = tid >> 4;     // n-octet: n = n0 + ty*8 + ni

    float acc[8][8];
#pragma unroll
    for (int i = 0; i < 8; ++i)
#pragma unroll
        for (int jj = 0; jj < 8; ++jj) acc[i][jj] = 0.0f;

    const int ar = tid >> 1;           // row 0..127 (for both A and W)
    const int ak = (tid & 1) * 16;     // k-half 0/16

    for (int k0 = 0; k0 < K; k0 += 32) {
        const float* ap = A + (size_t)(m0 + ar) * K + k0 + ak;
        float4 a0 = *(const float4*)(ap + 0);
        float4 a1 = *(const float4*)(ap + 4);
        float4 a2 = *(const float4*)(ap + 8);
        float4 a3 = *(const float4*)(ap + 12);
        const float* wp = W + (size_t)(n0 + ar) * K + k0 + ak;
        float4 w0 = *(const float4*)(wp + 0);
        float4 w1 = *(const float4*)(wp + 4);
        float4 w2 = *(const float4*)(wp + 8);
        float4 w3 = *(const float4*)(wp + 12);

        __syncthreads();
        {
            float av_[16] = {a0.x, a0.y, a0.z, a0.w, a1.x, a1.y, a1.z, a1.w,
                             a2.x, a2.y, a2.z, a2.w, a3.x, a3.y, a3.z, a3.w};
#pragma unroll
            for (int q = 0; q < 16; ++q) As[ak + q][ar] = av_[q];
            float wv_[16] = {w0.x, w0.y, w0.z, w0.w, w1.x, w1.y, w1.z, w1.w,
                             w2.x, w2.y, w2.z, w2.w, w3.x, w3.y, w3.z, w3.w};
#pragma unroll
            for (int q = 0; q < 16; ++q) Bs[ak + q][ar] = wv_[q];
        }
        __syncthreads();

#pragma unroll
        for (int kk = 0; kk < 32; ++kk) {
            float4 av0 = *(const float4*)&As[kk][tx * 4];        // m-quad 0
            float4 av1 = *(const float4*)&As[kk][64 + tx * 4];   // m-quad 1
            float4 bv0 = *(const float4*)&Bs[kk][ty * 8];
            float4 bv1 = *(const float4*)&Bs[kk][ty * 8 + 4];
            float am[8] = {av0.x, av0.y, av0.z, av0.w, av1.x, av1.y, av1.z, av1.w};
            float wn[8] = {bv0.x, bv0.y, bv0.z, bv0.w, bv1.x, bv1.y, bv1.z, bv1.w};
#pragma unroll
            for (int ni = 0; ni < 8; ++ni)
#pragma unroll
                for (int mi = 0; mi < 8; ++mi)
                    acc[ni][mi] = fmaf(am[mi], wn[ni], acc[ni][mi]);
        }
    }

    // epilogue: bias + prescale + transposed (dir=1 time-reversed) store
    const int dir = n0 >> 7;
#pragma unroll
    for (int ni = 0; ni < 8; ++ni) {
        const int n = n0 + ty * 8 + ni;
        const float bias = bi[n] + bh[n];
        const float sc = (((n >> 5) & 3) == 2) ? (-2.0f * LOG2E) : (-LOG2E);
        float* rowp = xpT + ((size_t)(dir * 32 * 128) + (n & 127)) * TB;
#pragma unroll
        for (int qd = 0; qd < 2; ++qd) {
            const int mq = m0 + qd * 64 + tx * 4;
            const int bidx = mq / 1000;       // quad never crosses b (4 | 1000)
            const int ttq = mq - bidx * 1000;
            float* rp = rowp + (size_t)bidx * 128 * TB;
            if (dir == 0) {
                float4 o = {(acc[ni][qd*4+0] + bias) * sc,
                            (acc[ni][qd*4+1] + bias) * sc,
                            (acc[ni][qd*4+2] + bias) * sc,
                            (acc[ni][qd*4+3] + bias) * sc};
                *(float4*)(rp + ttq) = o;
            } else {
                float4 o = {(acc[ni][qd*4+3] + bias) * sc,
                            (acc[ni][qd*4+2] + bias) * sc,
                            (acc[ni][qd*4+1] + bias) * sc,
                            (acc[ni][qd*4+0] + bias) * sc};
                *(float4*)(rp + (TB - 4 - ttq)) = o;
            }
        }
    }
}

// ---------------------------------------------------------------------------
// Recurrence (r15 verified): one wave per (dir,b). Lane l owns gate rows
// r0=(l&31)+(l>=32?64:0), r1=r0+32. h broadcast: ds_write_b32 + 8x
// ds_read_b128 with STAGED lgkmcnt waits. Gates prescaled: exp2 direct.
// cs = -2log2e * c tracked directly; h = fma(so+so, r, -so).
// ---------------------------------------------------------------------------
template<int MODE>
__global__ __launch_bounds__(64)
void lstm_rec(const float* __restrict__ xpT,  // [64][128][1000] prescaled
              const float* __restrict__ whh,  // [2][128][32]
              float* __restrict__ hout,       // [32][1000][64]
              float* __restrict__ hsum)       // [32][64]
{
    __shared__ __align__(16) float hsh[32];

    const int blk  = blockIdx.x;   // dir*32 + b
    const int dir  = blk >> 5;
    const int b    = blk & 31;
    const int lane = threadIdx.x & 63;
    const int j    = lane & 31;
    const int up   = lane >> 5;
    const int r0   = j + up * 64;
    const int r1   = r0 + 32;

    v2i det = __builtin_amdgcn_permlane32_swap(lane, lane, false, false);
    const bool pickx = (det[0] == (lane ^ 32));

    const float sA = up ? (-2.0f * LOG2E) : (-LOG2E);
    const float sB = -LOG2E;
    v2f wa[16], wb[16];
    {
        const float* wp0 = whh + (size_t)(dir * 128 + r0) * 32;
        const float* wp1 = whh + (size_t)(dir * 128 + r1) * 32;
#pragma unroll
        for (int q = 0; q < 8; ++q) {
            float4 v = *(const float4*)(wp0 + q * 4);
            wa[2 * q + 0][0] = v.x * sA; wa[2 * q + 0][1] = v.y * sA;
            wa[2 * q + 1][0] = v.z * sA; wa[2 * q + 1][1] = v.w * sA;
            float4 u = *(const float4*)(wp1 + q * 4);
            wb[2 * q + 0][0] = u.x * sB; wb[2 * q + 0][1] = u.y * sB;
            wb[2 * q + 1][0] = u.z * sB; wb[2 * q + 1][1] = u.w * sB;
        }
    }

    const float* pa = xpT + ((size_t)blk * 128 + r0) * TB;
    const float* pb = xpT + ((size_t)blk * 128 + r1) * TB;

    float4 A0 = *(const float4*)(pa + 0);
    float4 B0 = *(const float4*)(pb + 0);
    float4 A1 = *(const float4*)(pa + 4);
    float4 B1 = *(const float4*)(pb + 4);

    const float mA = up ?  2.0f : 1.0f;
    const float mB = up ? -1.0f : 0.0f;

    float cs = 0.0f, h = 0.0f, hacc = 0.0f;   // cs = -2log2e * c
    float* hq = hout + ((size_t)b * TB + (dir ? TB - 1 : 0)) * 64 + dir * 32 + j;
    const int hstep = dir ? -64 : 64;

    const unsigned lds_z  = (unsigned)(size_t)&hsh[0];
    const unsigned lds_wa = lds_z + 4u * (unsigned)j;

    float4 hv0, hv1, hv2, hv3, hv4v, hv5, hv6, hv7;

#define DS_WRITE_H() \
    asm volatile("ds_write_b32 %0, %1" :: "v"(lds_wa), "v"(h))

#define DS_ISSUE_READS() do {                                                   \
    asm volatile("ds_read_b128 %0, %1 offset:0"   : "=v"(hv0)  : "v"(lds_z));   \
    asm volatile("ds_read_b128 %0, %1 offset:16"  : "=v"(hv1)  : "v"(lds_z));   \
    asm volatile("ds_read_b128 %0, %1 offset:32"  : "=v"(hv2)  : "v"(lds_z));   \
    asm volatile("ds_read_b128 %0, %1 offset:48"  : "=v"(hv3)  : "v"(lds_z));   \
    asm volatile("ds_read_b128 %0, %1 offset:64"  : "=v"(hv4v) : "v"(lds_z));   \
    asm volatile("ds_read_b128 %0, %1 offset:80"  : "=v"(hv5)  : "v"(lds_z));   \
    asm volatile("ds_read_b128 %0, %1 offset:96"  : "=v"(hv6)  : "v"(lds_z));   \
    asm volatile("ds_read_b128 %0, %1 offset:112" : "=v"(hv7)  : "v"(lds_z));   \
    } while (0)

#define MVG(HV, CNT, I0, I1, Q)                                                 \
    asm volatile("s_waitcnt lgkmcnt(" #CNT ")");                                \
    __builtin_amdgcn_sched_barrier(0);                                          \
    {                                                                           \
        v2f h0_ = {HV.x, HV.y};                                                 \
        v2f h1_ = {HV.z, HV.w};                                                 \
        qa[I0] = __builtin_elementwise_fma(h0_, wa[2*Q],   qa[I0]);             \
        qb[I0] = __builtin_elementwise_fma(h0_, wb[2*Q],   qb[I0]);             \
        qa[I1] = __builtin_elementwise_fma(h1_, wa[2*Q+1], qa[I1]);             \
        qb[I1] = __builtin_elementwise_fma(h1_, wb[2*Q+1], qb[I1]);             \
    }

    DS_WRITE_H();
    DS_ISSUE_READS();

#define LSTM_STEP(GA, GB) do {                                                  \
        v2f qa[4], qb[4];                                                       \
        qa[0] = v2f{(GA), 0.0f}; qa[1] = v2f{0.f, 0.f};                         \
        qa[2] = v2f{0.f, 0.f};   qa[3] = v2f{0.f, 0.f};                         \
        qb[0] = v2f{(GB), 0.0f}; qb[1] = v2f{0.f, 0.f};                         \
        qb[2] = v2f{0.f, 0.f};   qb[3] = v2f{0.f, 0.f};                         \
        MVG(hv0,  7, 0, 1, 0)                                                   \
        MVG(hv1,  6, 2, 3, 1)                                                   \
        MVG(hv2,  5, 0, 1, 2)                                                   \
        MVG(hv3,  4, 2, 3, 3)                                                   \
        MVG(hv4v, 3, 0, 1, 4)                                                   \
        MVG(hv5,  2, 2, 3, 5)                                                   \
        MVG(hv6,  1, 0, 1, 6)                                                   \
        MVG(hv7,  0, 2, 3, 7)                                                   \
        v2f sa = (qa[0] + qa[2]) + (qa[1] + qa[3]);                             \
        v2f sb = (qb[0] + qb[2]) + (qb[1] + qb[3]);                             \
        float g0 = sa[0] + sa[1];                                               \
        float g1 = sb[0] + sb[1];                                               \
        float s0 = __builtin_amdgcn_rcpf(1.0f + fexp2(g0));                     \
        float v0 = fmaf(mA, s0, mB);   /* lo: sig(i); hi: tanh(g) */            \
        float v1 = __builtin_amdgcn_rcpf(1.0f + fexp2(g1)); /* sig(f)/sig(o) */ \
        float o0 = lane_xor32(v0, pickx);                                       \
        float o1 = lane_xor32(v1, pickx);                                       \
        float P  = v0 * o0;            /* == si*tg in BOTH halves */            \
        float Ps = P * (-2.0f * LOG2E);                                         \
        float sf = up ? o1 : v1;                                                \
        float so = up ? v1 : o1;                                                \
        cs = fmaf(sf, cs, Ps);         /* cs = -2log2e * c */                   \
        float r_ = __builtin_amdgcn_rcpf(1.0f + fexp2(cs));                     \
        float so2 = so + so;                                                    \
        h = fmaf(so2, r_, -so);        /* = so * tanh(c) */                     \
        DS_WRITE_H();                                                           \
        DS_ISSUE_READS();                                                       \
        if (MODE == 0) {                                                        \
            asm volatile("global_store_dword %0, %1, off" :: "v"(hq), "v"(h));  \
        } else {                                                                \
            hacc += h;                                                          \
        }                                                                       \
        hq += hstep;                                                            \
    } while (0)

    for (int it = 0; it < 125; ++it) {
        const int base = it * 8;
        const int offn0 = min(base + 8,  TB - 4);   // clamped, unconditional
        const int offn1 = min(base + 12, TB - 4);
        float4 NA0 = *(const float4*)(pa + offn0);
        float4 NB0 = *(const float4*)(pb + offn0);
        float4 NA1 = *(const float4*)(pa + offn1);
        float4 NB1 = *(const float4*)(pb + offn1);

        LSTM_STEP(A0.x, B0.x);
        LSTM_STEP(A0.y, B0.y);
        LSTM_STEP(A0.z, B0.z);
        LSTM_STEP(A0.w, B0.w);
        LSTM_STEP(A1.x, B1.x);
        LSTM_STEP(A1.y, B1.y);
        LSTM_STEP(A1.z, B1.z);
        LSTM_STEP(A1.w, B1.w);

        A0 = NA0; B0 = NB0; A1 = NA1; B1 = NB1;
    }
#undef LSTM_STEP
#undef MVG
#undef DS_ISSUE_READS
#undef DS_WRITE_H

    asm volatile("s_waitcnt lgkmcnt(0)" ::: "memory");

    if (MODE == 1) hsum[b * 64 + dir * 32 + j] = hacc;
}

// ---------------------------------------------------------------------------
__global__ __launch_bounds__(64)
void final_fc(const float* __restrict__ hsum,
              const float* __restrict__ fcw,
              const float* __restrict__ fcb,
              float* __restrict__ out)
{
    int b = blockIdx.x;
    int l = threadIdx.x;
    float v = hsum[b * 64 + l] * (1.0f / (float)TB) * fcw[l];
#pragma unroll
    for (int off = 32; off > 0; off >>= 1)
        v += __shfl_down(v, off, 64);
    if (l == 0) out[b] = v + fcb[0];
}

// ---------------------------------------------------------------------------
extern "C" void kernel_launch(void* const* d_in, const int* in_sizes, int n_in,
                              void* d_out, int out_size, void* d_ws, size_t ws_size,
                              hipStream_t stream)
{
    const float* x    = (const float*)d_in[0];
    const float* wih0 = (const float*)d_in[1];
    const float* whh0 = (const float*)d_in[2];
    const float* bih0 = (const float*)d_in[3];
    const float* bhh0 = (const float*)d_in[4];
    const float* wih  = (const float*)d_in[5];
    const float* whh  = (const float*)d_in[6];
    const float* bih  = (const float*)d_in[7];
    const float* bhh  = (const float*)d_in[8];
    const float* fcw  = (const float*)d_in[9];
    const float* fcb  = (const float*)d_in[10];
    float* out = (float*)d_out;

    float* ws = (float*)d_ws;
    float* xp = ws;                         // 64*128*1000 floats
    float* hb = ws + 8192000;               // 32*1000*64 floats
    float* hs = ws + 8192000 + 2048000;     // 32*64

    dim3 gb(250, 2);

    gemm_proj<<<gb, 256, 0, stream>>>(x, 1024, wih0, bih0, bhh0, xp);
    lstm_rec<0><<<64, 64, 0, stream>>>(xp, whh0, hb, hs);

    for (int l = 1; l < 4; ++l) {
        const float* wl  = wih + (size_t)(l - 1) * 2 * 128 * 64;
        const float* whl = whh + (size_t)(l - 1) * 2 * 128 * 32;
        const float* b1  = bih + (size_t)(l - 1) * 256;
        const float* b2  = bhh + (size_t)(l - 1) * 256;
        gemm_proj<<<gb, 256, 0, stream>>>(hb, 64, wl, b1, b2, xp);
        if (l == 3) lstm_rec<1><<<64, 64, 0, stream>>>(xp, whl, hb, hs);
        else        lstm_rec<0><<<64, 64, 0, stream>>>(xp, whl, hb, hs);
    }

    final_fc<<<32, 64, 0, stream>>>(hs, fcw, fcb, out);
}

// Round 23
// 1016.954 us; speedup vs baseline: 1.9542x; 1.0011x over previous
//
#include <hip/hip_runtime.h>

// Wav2Vec BLSTM: 4-layer bi-LSTM (B=32, T=1000, H=32, G=128) + mean-pool + fc.
//
// Round 23: revert to r20 verbatim (verified best, 1018 us).
// Post-mortem of r21/r22: holding asm-async load results across a
// high-register-pressure compute region is unsound (RA live-range splits
// can copy in-flight load destinations); prefetch-across-compute is closed
// on this compiler from every direction tried (r11/r13/r14/r16/r21/r22).
//  GEMM: 128x128 tile, 8x8 acc, conflict-reduced staging, r10 chunk order.
//  LSTM: 1 chain/wave, staged lgkmcnt LDS broadcast, cs-folded tail.

#define TB 1000
#define LOG2E 1.44269504088896340736f

typedef int   v2i __attribute__((ext_vector_type(2)));
typedef float v2f __attribute__((ext_vector_type(2)));

__device__ __forceinline__ float fexp2(float x) {
#if __has_builtin(__builtin_amdgcn_exp2f)
    return __builtin_amdgcn_exp2f(x);
#else
    return exp2f(x);
#endif
}

// returns v[lane ^ 32]; pickx precomputed per-lane (convention-independent)
__device__ __forceinline__ float lane_xor32(float v, bool pickx) {
    v2i r = __builtin_amdgcn_permlane32_swap(__float_as_int(v), __float_as_int(v),
                                             false, false);
    return __int_as_float(pickx ? r[0] : r[1]);
}

// ---------------------------------------------------------------------------
// GEMM: A[32000][K] x W[256][K]^T + (bi+bh), prescale by -log2e (g-rows:
// -2log2e) -> xpT[2*32][128][1000] (dir=1 time-reversed).
// 128m x 128n tile, 256 threads, acc[8n][8m] (m-quads at tx*4 and 64+tx*4),
// BK=32, r10 chunk order (the only allocator-safe schedule).
// ---------------------------------------------------------------------------
__global__ __launch_bounds__(256)
void gemm_proj(const float* __restrict__ A, int K,
               const float* __restrict__ W,
               const float* __restrict__ bi,
               const float* __restrict__ bh,
               float* __restrict__ xpT)
{
    __shared__ __align__(16) float As[32][132];   // [k][m]
    __shared__ __align__(16) float Bs[32][132];   // [k][n]

    const int tid = threadIdx.x;
    const int m0 = blockIdx.x * 128;
    const int n0 = blockIdx.y * 128;
    const int tx = tid & 15;     // m-quads: m = m0 + qd*64 + tx*4 + mi
    const int ty = tid >> 4;     // n-octet: n = n0 + ty*8 + ni

    float acc[8][8];
#pragma unroll
    for (int i = 0; i < 8; ++i)
#pragma unroll
        for (int jj = 0; jj < 8; ++jj) acc[i][jj] = 0.0f;

    const int ar = tid >> 1;           // row 0..127 (for both A and W)
    const int ak = (tid & 1) * 16;     // k-half 0/16

    for (int k0 = 0; k0 < K; k0 += 32) {
        const float* ap = A + (size_t)(m0 + ar) * K + k0 + ak;
        float4 a0 = *(const float4*)(ap + 0);
        float4 a1 = *(const float4*)(ap + 4);
        float4 a2 = *(const float4*)(ap + 8);
        float4 a3 = *(const float4*)(ap + 12);
        const float* wp = W + (size_t)(n0 + ar) * K + k0 + ak;
        float4 w0 = *(const float4*)(wp + 0);
        float4 w1 = *(const float4*)(wp + 4);
        float4 w2 = *(const float4*)(wp + 8);
        float4 w3 = *(const float4*)(wp + 12);

        __syncthreads();
        {
            float av_[16] = {a0.x, a0.y, a0.z, a0.w, a1.x, a1.y, a1.z, a1.w,
                             a2.x, a2.y, a2.z, a2.w, a3.x, a3.y, a3.z, a3.w};
#pragma unroll
            for (int q = 0; q < 16; ++q) As[ak + q][ar] = av_[q];
            float wv_[16] = {w0.x, w0.y, w0.z, w0.w, w1.x, w1.y, w1.z, w1.w,
                             w2.x, w2.y, w2.z, w2.w, w3.x, w3.y, w3.z, w3.w};
#pragma unroll
            for (int q = 0; q < 16; ++q) Bs[ak + q][ar] = wv_[q];
        }
        __syncthreads();

#pragma unroll
        for (int kk = 0; kk < 32; ++kk) {
            float4 av0 = *(const float4*)&As[kk][tx * 4];        // m-quad 0
            float4 av1 = *(const float4*)&As[kk][64 + tx * 4];   // m-quad 1
            float4 bv0 = *(const float4*)&Bs[kk][ty * 8];
            float4 bv1 = *(const float4*)&Bs[kk][ty * 8 + 4];
            float am[8] = {av0.x, av0.y, av0.z, av0.w, av1.x, av1.y, av1.z, av1.w};
            float wn[8] = {bv0.x, bv0.y, bv0.z, bv0.w, bv1.x, bv1.y, bv1.z, bv1.w};
#pragma unroll
            for (int ni = 0; ni < 8; ++ni)
#pragma unroll
                for (int mi = 0; mi < 8; ++mi)
                    acc[ni][mi] = fmaf(am[mi], wn[ni], acc[ni][mi]);
        }
    }

    // epilogue: bias + prescale + transposed (dir=1 time-reversed) store
    const int dir = n0 >> 7;
#pragma unroll
    for (int ni = 0; ni < 8; ++ni) {
        const int n = n0 + ty * 8 + ni;
        const float bias = bi[n] + bh[n];
        const float sc = (((n >> 5) & 3) == 2) ? (-2.0f * LOG2E) : (-LOG2E);
        float* rowp = xpT + ((size_t)(dir * 32 * 128) + (n & 127)) * TB;
#pragma unroll
        for (int qd = 0; qd < 2; ++qd) {
            const int mq = m0 + qd * 64 + tx * 4;
            const int bidx = mq / 1000;       // quad never crosses b (4 | 1000)
            const int ttq = mq - bidx * 1000;
            float* rp = rowp + (size_t)bidx * 128 * TB;
            if (dir == 0) {
                float4 o = {(acc[ni][qd*4+0] + bias) * sc,
                            (acc[ni][qd*4+1] + bias) * sc,
                            (acc[ni][qd*4+2] + bias) * sc,
                            (acc[ni][qd*4+3] + bias) * sc};
                *(float4*)(rp + ttq) = o;
            } else {
                float4 o = {(acc[ni][qd*4+3] + bias) * sc,
                            (acc[ni][qd*4+2] + bias) * sc,
                            (acc[ni][qd*4+1] + bias) * sc,
                            (acc[ni][qd*4+0] + bias) * sc};
                *(float4*)(rp + (TB - 4 - ttq)) = o;
            }
        }
    }
}

// ---------------------------------------------------------------------------
// Recurrence (r15/r20 verified): one wave per (dir,b). Lane l owns gate rows
// r0=(l&31)+(l>=32?64:0), r1=r0+32. h broadcast: ds_write_b32 + 8x
// ds_read_b128 with STAGED lgkmcnt waits. Gates prescaled: exp2 direct.
// cs = -2log2e * c tracked directly; h = fma(so+so, r, -so).
// ---------------------------------------------------------------------------
template<int MODE>
__global__ __launch_bounds__(64)
void lstm_rec(const float* __restrict__ xpT,  // [64][128][1000] prescaled
              const float* __restrict__ whh,  // [2][128][32]
              float* __restrict__ hout,       // [32][1000][64]
              float* __restrict__ hsum)       // [32][64]
{
    __shared__ __align__(16) float hsh[32];

    const int blk  = blockIdx.x;   // dir*32 + b
    const int dir  = blk >> 5;
    const int b    = blk & 31;
    const int lane = threadIdx.x & 63;
    const int j    = lane & 31;
    const int up   = lane >> 5;
    const int r0   = j + up * 64;
    const int r1   = r0 + 32;

    v2i det = __builtin_amdgcn_permlane32_swap(lane, lane, false, false);
    const bool pickx = (det[0] == (lane ^ 32));

    const float sA = up ? (-2.0f * LOG2E) : (-LOG2E);
    const float sB = -LOG2E;
    v2f wa[16], wb[16];
    {
        const float* wp0 = whh + (size_t)(dir * 128 + r0) * 32;
        const float* wp1 = whh + (size_t)(dir * 128 + r1) * 32;
#pragma unroll
        for (int q = 0; q < 8; ++q) {
            float4 v = *(const float4*)(wp0 + q * 4);
            wa[2 * q + 0][0] = v.x * sA; wa[2 * q + 0][1] = v.y * sA;
            wa[2 * q + 1][0] = v.z * sA; wa[2 * q + 1][1] = v.w * sA;
            float4 u = *(const float4*)(wp1 + q * 4);
            wb[2 * q + 0][0] = u.x * sB; wb[2 * q + 0][1] = u.y * sB;
            wb[2 * q + 1][0] = u.z * sB; wb[2 * q + 1][1] = u.w * sB;
        }
    }

    const float* pa = xpT + ((size_t)blk * 128 + r0) * TB;
    const float* pb = xpT + ((size_t)blk * 128 + r1) * TB;

    float4 A0 = *(const float4*)(pa + 0);
    float4 B0 = *(const float4*)(pb + 0);
    float4 A1 = *(const float4*)(pa + 4);
    float4 B1 = *(const float4*)(pb + 4);

    const float mA = up ?  2.0f : 1.0f;
    const float mB = up ? -1.0f : 0.0f;

    float cs = 0.0f, h = 0.0f, hacc = 0.0f;   // cs = -2log2e * c
    float* hq = hout + ((size_t)b * TB + (dir ? TB - 1 : 0)) * 64 + dir * 32 + j;
    const int hstep = dir ? -64 : 64;

    const unsigned lds_z  = (unsigned)(size_t)&hsh[0];
    const unsigned lds_wa = lds_z + 4u * (unsigned)j;

    float4 hv0, hv1, hv2, hv3, hv4v, hv5, hv6, hv7;

#define DS_WRITE_H() \
    asm volatile("ds_write_b32 %0, %1" :: "v"(lds_wa), "v"(h))

#define DS_ISSUE_READS() do {                                                   \
    asm volatile("ds_read_b128 %0, %1 offset:0"   : "=v"(hv0)  : "v"(lds_z));   \
    asm volatile("ds_read_b128 %0, %1 offset:16"  : "=v"(hv1)  : "v"(lds_z));   \
    asm volatile("ds_read_b128 %0, %1 offset:32"  : "=v"(hv2)  : "v"(lds_z));   \
    asm volatile("ds_read_b128 %0, %1 offset:48"  : "=v"(hv3)  : "v"(lds_z));   \
    asm volatile("ds_read_b128 %0, %1 offset:64"  : "=v"(hv4v) : "v"(lds_z));   \
    asm volatile("ds_read_b128 %0, %1 offset:80"  : "=v"(hv5)  : "v"(lds_z));   \
    asm volatile("ds_read_b128 %0, %1 offset:96"  : "=v"(hv6)  : "v"(lds_z));   \
    asm volatile("ds_read_b128 %0, %1 offset:112" : "=v"(hv7)  : "v"(lds_z));   \
    } while (0)

#define MVG(HV, CNT, I0, I1, Q)                                                 \
    asm volatile("s_waitcnt lgkmcnt(" #CNT ")");                                \
    __builtin_amdgcn_sched_barrier(0);                                          \
    {                                                                           \
        v2f h0_ = {HV.x, HV.y};                                                 \
        v2f h1_ = {HV.z, HV.w};                                                 \
        qa[I0] = __builtin_elementwise_fma(h0_, wa[2*Q],   qa[I0]);             \
        qb[I0] = __builtin_elementwise_fma(h0_, wb[2*Q],   qb[I0]);             \
        qa[I1] = __builtin_elementwise_fma(h1_, wa[2*Q+1], qa[I1]);             \
        qb[I1] = __builtin_elementwise_fma(h1_, wb[2*Q+1], qb[I1]);             \
    }

    DS_WRITE_H();
    DS_ISSUE_READS();

#define LSTM_STEP(GA, GB) do {                                                  \
        v2f qa[4], qb[4];                                                       \
        qa[0] = v2f{(GA), 0.0f}; qa[1] = v2f{0.f, 0.f};                         \
        qa[2] = v2f{0.f, 0.f};   qa[3] = v2f{0.f, 0.f};                         \
        qb[0] = v2f{(GB), 0.0f}; qb[1] = v2f{0.f, 0.f};                         \
        qb[2] = v2f{0.f, 0.f};   qb[3] = v2f{0.f, 0.f};                         \
        MVG(hv0,  7, 0, 1, 0)                                                   \
        MVG(hv1,  6, 2, 3, 1)                                                   \
        MVG(hv2,  5, 0, 1, 2)                                                   \
        MVG(hv3,  4, 2, 3, 3)                                                   \
        MVG(hv4v, 3, 0, 1, 4)                                                   \
        MVG(hv5,  2, 2, 3, 5)                                                   \
        MVG(hv6,  1, 0, 1, 6)                                                   \
        MVG(hv7,  0, 2, 3, 7)                                                   \
        v2f sa = (qa[0] + qa[2]) + (qa[1] + qa[3]);                             \
        v2f sb = (qb[0] + qb[2]) + (qb[1] + qb[3]);                             \
        float g0 = sa[0] + sa[1];                                               \
        float g1 = sb[0] + sb[1];                                               \
        float s0 = __builtin_amdgcn_rcpf(1.0f + fexp2(g0));                     \
        float v0 = fmaf(mA, s0, mB);   /* lo: sig(i); hi: tanh(g) */            \
        float v1 = __builtin_amdgcn_rcpf(1.0f + fexp2(g1)); /* sig(f)/sig(o) */ \
        float o0 = lane_xor32(v0, pickx);                                       \
        float o1 = lane_xor32(v1, pickx);                                       \
        float P  = v0 * o0;            /* == si*tg in BOTH halves */            \
        float Ps = P * (-2.0f * LOG2E);                                         \
        float sf = up ? o1 : v1;                                                \
        float so = up ? v1 : o1;                                                \
        cs = fmaf(sf, cs, Ps);         /* cs = -2log2e * c */                   \
        float r_ = __builtin_amdgcn_rcpf(1.0f + fexp2(cs));                     \
        float so2 = so + so;                                                    \
        h = fmaf(so2, r_, -so);        /* = so * tanh(c) */                     \
        DS_WRITE_H();                                                           \
        DS_ISSUE_READS();                                                       \
        if (MODE == 0) {                                                        \
            asm volatile("global_store_dword %0, %1, off" :: "v"(hq), "v"(h));  \
        } else {                                                                \
            hacc += h;                                                          \
        }                                                                       \
        hq += hstep;                                                            \
    } while (0)

    for (int it = 0; it < 125; ++it) {
        const int base = it * 8;
        const int offn0 = min(base + 8,  TB - 4);   // clamped, unconditional
        const int offn1 = min(base + 12, TB - 4);
        float4 NA0 = *(const float4*)(pa + offn0);
        float4 NB0 = *(const float4*)(pb + offn0);
        float4 NA1 = *(const float4*)(pa + offn1);
        float4 NB1 = *(const float4*)(pb + offn1);

        LSTM_STEP(A0.x, B0.x);
        LSTM_STEP(A0.y, B0.y);
        LSTM_STEP(A0.z, B0.z);
        LSTM_STEP(A0.w, B0.w);
        LSTM_STEP(A1.x, B1.x);
        LSTM_STEP(A1.y, B1.y);
        LSTM_STEP(A1.z, B1.z);
        LSTM_STEP(A1.w, B1.w);

        A0 = NA0; B0 = NB0; A1 = NA1; B1 = NB1;
    }
#undef LSTM_STEP
#undef MVG
#undef DS_ISSUE_READS
#undef DS_WRITE_H

    asm volatile("s_waitcnt lgkmcnt(0)" ::: "memory");

    if (MODE == 1) hsum[b * 64 + dir * 32 + j] = hacc;
}

// ---------------------------------------------------------------------------
__global__ __launch_bounds__(64)
void final_fc(const float* __restrict__ hsum,
              const float* __restrict__ fcw,
              const float* __restrict__ fcb,
              float* __restrict__ out)
{
    int b = blockIdx.x;
    int l = threadIdx.x;
    float v = hsum[b * 64 + l] * (1.0f / (float)TB) * fcw[l];
#pragma unroll
    for (int off = 32; off > 0; off >>= 1)
        v += __shfl_down(v, off, 64);
    if (l == 0) out[b] = v + fcb[0];
}

// ---------------------------------------------------------------------------
extern "C" void kernel_launch(void* const* d_in, const int* in_sizes, int n_in,
                              void* d_out, int out_size, void* d_ws, size_t ws_size,
                              hipStream_t stream)
{
    const float* x    = (const float*)d_in[0];
    const float* wih0 = (const float*)d_in[1];
    const float* whh0 = (const float*)d_in[2];
    const float* bih0 = (const float*)d_in[3];
    const float* bhh0 = (const float*)d_in[4];
    const float* wih  = (const float*)d_in[5];
    const float* whh  = (const float*)d_in[6];
    const float* bih  = (const float*)d_in[7];
    const float* bhh  = (const float*)d_in[8];
    const float* fcw  = (const float*)d_in[9];
    const float* fcb  = (const float*)d_in[10];
    float* out = (float*)d_out;

    float* ws = (float*)d_ws;
    float* xp = ws;                         // 64*128*1000 floats
    float* hb = ws + 8192000;               // 32*1000*64 floats
    float* hs = ws + 8192000 + 2048000;     // 32*64

    dim3 gb(250, 2);

    gemm_proj<<<gb, 256, 0, stream>>>(x, 1024, wih0, bih0, bhh0, xp);
    lstm_rec<0><<<64, 64, 0, stream>>>(xp, whh0, hb, hs);

    for (int l = 1; l < 4; ++l) {
        const float* wl  = wih + (size_t)(l - 1) * 2 * 128 * 64;
        const float* whl = whh + (size_t)(l - 1) * 2 * 128 * 32;
        const float* b1  = bih + (size_t)(l - 1) * 256;
        const float* b2  = bhh + (size_t)(l - 1) * 256;
        gemm_proj<<<gb, 256, 0, stream>>>(hb, 64, wl, b1, b2, xp);
        if (l == 3) lstm_rec<1><<<64, 64, 0, stream>>>(xp, whl, hb, hs);
        else        lstm_rec<0><<<64, 64, 0, stream>>>(xp, whl, hb, hs);
    }

    final_fc<<<32, 64, 0, stream>>>(hs, fcw, fcb, out);
}